// Round 1
// baseline (5764.785 us; speedup 1.0000x reference)
//
#include <hip/hip_runtime.h>
#include <math.h>

#define D 1024
#define E 64
#define TOPK 6
#define NTOK 1024          // B*T = 2*512
#define F_R 704
#define F_S 1408
#define TM 32
#define MAXTILES 8         // supports up to 256 tokens per expert (mean 96, std ~9)

__device__ __forceinline__ float sigm(float v) { return 1.f / (1.f + __expf(-v)); }

// ---------------- Gate: logits, sigmoid, scores out, top-6, normalize ----------------
__global__ __launch_bounds__(64) void gate_kernel(
    const float* __restrict__ x, const float* __restrict__ wg,
    const float* __restrict__ gb, float* __restrict__ scores,
    int* __restrict__ sel_idx, float* __restrict__ sel_w)
{
    int t = blockIdx.x;
    int tid = threadIdx.x;
    __shared__ float xs[D];
    __shared__ float sc[E];
    for (int i = tid; i < D; i += 64) xs[i] = x[(size_t)t * D + i];
    __syncthreads();

    const float4* wrow = (const float4*)(wg + (size_t)tid * D);
    const float4* xv = (const float4*)xs;
    float acc = 0.f;
    for (int i = 0; i < D / 4; ++i) {
        float4 a = xv[i]; float4 b = wrow[i];
        acc += a.x * b.x + a.y * b.y + a.z * b.z + a.w * b.w;
    }
    float s = sigm(acc) + gb[tid];
    sc[tid] = s;
    scores[(size_t)t * E + tid] = s;
    __syncthreads();

    if (tid == 0) {
        int idxs[TOPK]; float vals[TOPK]; float wsum = 0.f;
        for (int k = 0; k < TOPK; ++k) {
            float best = -1e30f; int bi = 0;
            for (int e = 0; e < E; ++e) {
                if (sc[e] > best) { best = sc[e]; bi = e; }
            }
            sc[bi] = -1e30f;
            idxs[k] = bi; vals[k] = best; wsum += best;
        }
        float inv = 1.f / wsum;
        for (int k = 0; k < TOPK; ++k) {
            sel_idx[t * TOPK + k] = idxs[k];
            sel_w[t * TOPK + k] = vals[k] * inv;
        }
    }
}

// ---------------- Routing lists ----------------
__global__ void count_kernel(const int* __restrict__ sel_idx, int* __restrict__ counts) {
    int i = blockIdx.x * blockDim.x + threadIdx.x;
    if (i < NTOK * TOPK) atomicAdd(&counts[sel_idx[i]], 1);
}

__global__ void scan_kernel(const int* __restrict__ counts, int* __restrict__ offsets) {
    if (threadIdx.x == 0 && blockIdx.x == 0) {
        int run = 0;
        for (int e = 0; e < E; ++e) { offsets[e] = run; run += counts[e]; }
    }
}

__global__ void scatter_kernel(const int* __restrict__ sel_idx, const float* __restrict__ sel_w,
                               const int* __restrict__ offsets, int* __restrict__ cursor,
                               int* __restrict__ slot_tok, float* __restrict__ slot_w) {
    int i = blockIdx.x * blockDim.x + threadIdx.x;
    if (i < NTOK * TOPK) {
        int e = sel_idx[i];
        int pos = offsets[e] + atomicAdd(&cursor[e], 1);
        slot_tok[pos] = i / TOPK;
        slot_w[pos] = sel_w[i];
    }
}

// ---------------- GEMM A: G = silu(X@W1) * (X@W3), gathered rows ----------------
// block: 256 thr = 64 f-lanes x 4 token-groups; tile: TM=32 tokens x 64 f-cols
template <int F, bool GATHER>
__global__ __launch_bounds__(256) void gemmA(
    const float* __restrict__ x, const float* __restrict__ w1, const float* __restrict__ w3,
    const int* __restrict__ offsets, const int* __restrict__ counts,
    const int* __restrict__ slot_tok, float* __restrict__ G)
{
    int e = blockIdx.z;
    int off, n;
    if (GATHER) {
        off = offsets[e]; n = counts[e];
        if (n > TM * MAXTILES) n = TM * MAXTILES;
    } else { off = 0; n = NTOK; }
    int m0 = blockIdx.x * TM;
    if (m0 >= n) return;
    int rows = min(TM, n - m0);
    int f0 = blockIdx.y * 64;
    int tid = threadIdx.x;
    int fj = tid & 63, tq = tid >> 6;

    __shared__ float xs[TM][128];
    __shared__ int toks[TM];
    if (tid < TM) {
        int r = tid;
        toks[r] = GATHER ? slot_tok[off + m0 + (r < rows ? r : 0)] : (m0 + r);
    }

    float acc1[8], acc3[8];
#pragma unroll
    for (int i = 0; i < 8; ++i) { acc1[i] = 0.f; acc3[i] = 0.f; }

    const size_t wbase = GATHER ? ((size_t)e * D * F) : 0;

    for (int d0 = 0; d0 < D; d0 += 128) {
        __syncthreads();   // protects xs reuse; also makes toks visible on iter 0
        for (int i = tid; i < TM * 128; i += 256) {
            int r = i >> 7, c = i & 127;
            xs[r][c] = x[(size_t)toks[r] * D + d0 + c];
        }
        __syncthreads();

        const float* w1p = w1 + wbase + (size_t)d0 * F + f0 + fj;
        const float* w3p = w3 + wbase + (size_t)d0 * F + f0 + fj;
        for (int dd = 0; dd < 128; dd += 4) {
            float4 xv[8];
#pragma unroll
            for (int i = 0; i < 8; ++i) xv[i] = *(const float4*)&xs[tq + 4 * i][dd];
#pragma unroll
            for (int j = 0; j < 4; ++j) {
                float w1v = w1p[(size_t)(dd + j) * F];
                float w3v = w3p[(size_t)(dd + j) * F];
#pragma unroll
                for (int i = 0; i < 8; ++i) {
                    float xvv = (j == 0) ? xv[i].x : (j == 1) ? xv[i].y : (j == 2) ? xv[i].z : xv[i].w;
                    acc1[i] = fmaf(xvv, w1v, acc1[i]);
                    acc3[i] = fmaf(xvv, w3v, acc3[i]);
                }
            }
        }
    }

#pragma unroll
    for (int i = 0; i < 8; ++i) {
        int r = tq + 4 * i;
        if (r < rows) {
            float a = acc1[i];
            float g = a * (1.f / (1.f + __expf(-a))) * acc3[i];
            G[(size_t)(off + m0 + r) * F + f0 + fj] = g;
        }
    }
}

// ---------------- GEMM B: out += w * (G @ W2) ----------------
// block: 256 thr = 64 d-lanes x 4 token-groups; tile: TM=32 tokens x 128 d-cols (2 per thread)
template <int F, bool GATHER>
__global__ __launch_bounds__(256) void gemmB(
    const float* __restrict__ G, const float* __restrict__ w2,
    const int* __restrict__ offsets, const int* __restrict__ counts,
    const int* __restrict__ slot_tok, const float* __restrict__ slot_w,
    float* __restrict__ out)
{
    int e = blockIdx.z;
    int off, n;
    if (GATHER) {
        off = offsets[e]; n = counts[e];
        if (n > TM * MAXTILES) n = TM * MAXTILES;
    } else { off = 0; n = NTOK; }
    int m0 = blockIdx.x * TM;
    if (m0 >= n) return;
    int rows = min(TM, n - m0);
    int d0 = blockIdx.y * 128;
    int tid = threadIdx.x;
    int dj = tid & 63, tq = tid >> 6;

    __shared__ float gs[TM][64];
    float acc[8][2];
#pragma unroll
    for (int i = 0; i < 8; ++i) { acc[i][0] = 0.f; acc[i][1] = 0.f; }

    const size_t wbase = GATHER ? ((size_t)e * F * D) : 0;

    for (int k0 = 0; k0 < F; k0 += 64) {
        __syncthreads();
        for (int i = tid; i < TM * 64; i += 256) {
            int r = i >> 6, c = i & 63;
            int s = off + m0 + (r < rows ? r : 0);
            gs[r][c] = G[(size_t)s * F + k0 + c];
        }
        __syncthreads();

        const float* w2p = w2 + wbase + (size_t)k0 * D + d0 + dj;
        for (int kk = 0; kk < 64; kk += 4) {
            float4 gv[8];
#pragma unroll
            for (int i = 0; i < 8; ++i) gv[i] = *(const float4*)&gs[tq + 4 * i][kk];
#pragma unroll
            for (int j = 0; j < 4; ++j) {
                float w2a = w2p[(size_t)(kk + j) * D];
                float w2b = w2p[(size_t)(kk + j) * D + 64];
#pragma unroll
                for (int i = 0; i < 8; ++i) {
                    float g = (j == 0) ? gv[i].x : (j == 1) ? gv[i].y : (j == 2) ? gv[i].z : gv[i].w;
                    acc[i][0] = fmaf(g, w2a, acc[i][0]);
                    acc[i][1] = fmaf(g, w2b, acc[i][1]);
                }
            }
        }
    }

#pragma unroll
    for (int i = 0; i < 8; ++i) {
        int r = tq + 4 * i;
        if (r < rows) {
            if (GATHER) {
                int sl = off + m0 + r;
                int tok = slot_tok[sl];
                float tw = slot_w[sl];
                atomicAdd(&out[(size_t)tok * D + d0 + dj], tw * acc[i][0]);
                atomicAdd(&out[(size_t)tok * D + d0 + dj + 64], tw * acc[i][1]);
            } else {
                out[(size_t)(m0 + r) * D + d0 + dj] = acc[i][0];
                out[(size_t)(m0 + r) * D + d0 + dj + 64] = acc[i][1];
            }
        }
    }
}

// ---------------- Launch ----------------
extern "C" void kernel_launch(void* const* d_in, const int* in_sizes, int n_in,
                              void* d_out, int out_size, void* d_ws, size_t ws_size,
                              hipStream_t stream)
{
    const float* x   = (const float*)d_in[0];
    const float* wg  = (const float*)d_in[1];
    const float* gb  = (const float*)d_in[2];
    const float* w1s = (const float*)d_in[3];
    const float* w2s = (const float*)d_in[4];
    const float* w3s = (const float*)d_in[5];
    const float* w1r = (const float*)d_in[6];
    const float* w2r = (const float*)d_in[7];
    const float* w3r = (const float*)d_in[8];

    float* out = (float*)d_out;                 // [NTOK, D]
    float* scores = out + (size_t)NTOK * D;     // [NTOK, E]

    char* ws = (char*)d_ws;
    int*   sel_idx  = (int*)(ws + 0);           // 6144 ints
    float* sel_w    = (float*)(ws + 24576);     // 6144 floats
    int*   counts   = (int*)(ws + 49152);       // 64
    int*   cursor   = (int*)(ws + 49408);       // 64
    int*   offsets  = (int*)(ws + 49664);       // 64
    int*   slot_tok = (int*)(ws + 49920);       // 6144
    float* slot_w   = (float*)(ws + 74496);     // 6144
    float* G_r      = (float*)(ws + 131072);                                  // 6144*704 f32 = 17.3 MB
    float* G_s      = (float*)(ws + 131072 + (size_t)NTOK * TOPK * F_R * 4);  // 1024*1408 f32 = 5.8 MB

    // zero counts + cursor
    hipMemsetAsync(counts, 0, 512, stream);

    gate_kernel<<<NTOK, 64, 0, stream>>>(x, wg, gb, scores, sel_idx, sel_w);
    count_kernel<<<24, 256, 0, stream>>>(sel_idx, counts);
    scan_kernel<<<1, 64, 0, stream>>>(counts, offsets);
    scatter_kernel<<<24, 256, 0, stream>>>(sel_idx, sel_w, offsets, cursor, slot_tok, slot_w);

    // routed experts: G = silu(X W1) * (X W3)
    gemmA<F_R, true><<<dim3(MAXTILES, F_R / 64, E), 256, 0, stream>>>(
        x, w1r, w3r, offsets, counts, slot_tok, G_r);
    // shared expert
    gemmA<F_S, false><<<dim3(NTOK / TM, F_S / 64, 1), 256, 0, stream>>>(
        x, w1s, w3s, offsets, counts, slot_tok, G_s);

    // shared expert writes out (plain store) first, routed atomic-adds after
    gemmB<F_S, false><<<dim3(NTOK / TM, D / 128, 1), 256, 0, stream>>>(
        G_s, w2s, offsets, counts, slot_tok, slot_w, out);
    gemmB<F_R, true><<<dim3(MAXTILES, D / 128, E), 256, 0, stream>>>(
        G_r, w2r, offsets, counts, slot_tok, slot_w, out);
}

// Round 2
// 3096.700 us; speedup vs baseline: 1.8616x; 1.8616x over previous
//
#include <hip/hip_runtime.h>
#include <math.h>

#define D 1024
#define E 64
#define TOPK 6
#define NTOK 1024          // B*T = 2*512
#define F_R 704
#define F_S 1408
#define BM 64              // token rows per block
#define MTILES 4           // supports up to 256 tokens per expert (mean 96, sd ~9.5)

__device__ __forceinline__ float sigm(float v) { return 1.f / (1.f + __expf(-v)); }

// ---------------- Gate: logits, sigmoid, scores out, top-6, normalize ----------------
__global__ __launch_bounds__(64) void gate_kernel(
    const float* __restrict__ x, const float* __restrict__ wg,
    const float* __restrict__ gb, float* __restrict__ scores,
    int* __restrict__ sel_idx, float* __restrict__ sel_w)
{
    int t = blockIdx.x;
    int tid = threadIdx.x;
    __shared__ float xs[D];
    __shared__ float sc[E];
    for (int i = tid; i < D; i += 64) xs[i] = x[(size_t)t * D + i];
    __syncthreads();

    const float4* wrow = (const float4*)(wg + (size_t)tid * D);
    const float4* xv = (const float4*)xs;
    float acc = 0.f;
    for (int i = 0; i < D / 4; ++i) {
        float4 a = xv[i]; float4 b = wrow[i];
        acc += a.x * b.x + a.y * b.y + a.z * b.z + a.w * b.w;
    }
    float s = sigm(acc) + gb[tid];
    sc[tid] = s;
    scores[(size_t)t * E + tid] = s;
    __syncthreads();

    if (tid == 0) {
        int idxs[TOPK]; float vals[TOPK]; float wsum = 0.f;
        for (int k = 0; k < TOPK; ++k) {
            float best = -1e30f; int bi = 0;
            for (int e = 0; e < E; ++e) {
                if (sc[e] > best) { best = sc[e]; bi = e; }
            }
            sc[bi] = -1e30f;
            idxs[k] = bi; vals[k] = best; wsum += best;
        }
        float inv = 1.f / wsum;
        for (int k = 0; k < TOPK; ++k) {
            sel_idx[t * TOPK + k] = idxs[k];
            sel_w[t * TOPK + k] = vals[k] * inv;
        }
    }
}

// ---------------- Routing lists ----------------
__global__ void count_kernel(const int* __restrict__ sel_idx, int* __restrict__ counts) {
    int i = blockIdx.x * blockDim.x + threadIdx.x;
    if (i < NTOK * TOPK) atomicAdd(&counts[sel_idx[i]], 1);
}

__global__ void scan_kernel(const int* __restrict__ counts, int* __restrict__ offsets) {
    if (threadIdx.x == 0 && blockIdx.x == 0) {
        int run = 0;
        for (int e = 0; e < E; ++e) { offsets[e] = run; run += counts[e]; }
    }
}

__global__ void scatter_kernel(const int* __restrict__ sel_idx, const float* __restrict__ sel_w,
                               const int* __restrict__ offsets, int* __restrict__ cursor,
                               int* __restrict__ slot_tok, float* __restrict__ slot_w) {
    int i = blockIdx.x * blockDim.x + threadIdx.x;
    if (i < NTOK * TOPK) {
        int e = sel_idx[i];
        int pos = offsets[e] + atomicAdd(&cursor[e], 1);
        slot_tok[pos] = i / TOPK;
        slot_w[pos] = sel_w[i];
    }
}

// ---------------- GEMM A: G = silu(X@W1) * (X@W3), gathered rows ----------------
// block 256 thr; tile BM=64 tokens x 128 f-cols. Thread: 16 rows x 2 cols x {w1,w3}.
template <int F, bool GATHER>
__global__ __launch_bounds__(256, 3) void gemmA(
    const float* __restrict__ x, const float* __restrict__ w1, const float* __restrict__ w3,
    const int* __restrict__ offsets, const int* __restrict__ counts,
    const int* __restrict__ slot_tok, float* __restrict__ G)
{
    int e = blockIdx.z;
    int off, n;
    if (GATHER) {
        off = offsets[e]; n = counts[e];
        if (n > BM * MTILES) n = BM * MTILES;
    } else { off = 0; n = NTOK; }
    int m0 = blockIdx.x * BM;
    if (m0 >= n) return;
    int rows = min(BM, n - m0);
    int f0 = blockIdx.y * 128;
    int tid = threadIdx.x;
    int fj = tid & 63, tq = tid >> 6;     // tq: row group 16 rows
    int f = f0 + fj * 2;
    int fc = min(f, F - 2);               // clamped address (F even)
    bool fvalid = (f <= F - 2);

    __shared__ float xs[BM][64];          // 16 KB
    __shared__ int toks[BM];
    if (tid < BM) {
        int r = min(tid, rows - 1);
        toks[tid] = GATHER ? slot_tok[off + m0 + r] : (m0 + r);
    }

    float acc1[16][2], acc3[16][2];
#pragma unroll
    for (int i = 0; i < 16; ++i) { acc1[i][0] = acc1[i][1] = 0.f; acc3[i][0] = acc3[i][1] = 0.f; }

    const size_t wbase = GATHER ? ((size_t)e * D * F) : 0;

    for (int k0 = 0; k0 < D; k0 += 64) {
        __syncthreads();
        // stage x tile: 64 rows x 64 cols = 1024 float4; 4 per thread
        for (int i = tid; i < BM * 16; i += 256) {
            int r = i >> 4, c4 = (i & 15) * 4;
            *(float4*)&xs[r][c4] = *(const float4*)&x[(size_t)toks[r] * D + k0 + c4];
        }
        __syncthreads();

        const float* w1p = w1 + wbase + (size_t)k0 * F + fc;
        const float* w3p = w3 + wbase + (size_t)k0 * F + fc;
#pragma unroll 2
        for (int kk = 0; kk < 64; kk += 4) {
            float2 w1v[4], w3v[4];
#pragma unroll
            for (int j = 0; j < 4; ++j) {
                w1v[j] = *(const float2*)&w1p[(size_t)(kk + j) * F];
                w3v[j] = *(const float2*)&w3p[(size_t)(kk + j) * F];
            }
#pragma unroll
            for (int h = 0; h < 2; ++h) {           // two 8-row halves
                float4 xv[8];
#pragma unroll
                for (int i = 0; i < 8; ++i) xv[i] = *(const float4*)&xs[tq * 16 + h * 8 + i][kk];
#pragma unroll
                for (int j = 0; j < 4; ++j) {
#pragma unroll
                    for (int i = 0; i < 8; ++i) {
                        float xi = (j == 0) ? xv[i].x : (j == 1) ? xv[i].y : (j == 2) ? xv[i].z : xv[i].w;
                        int ri = h * 8 + i;
                        acc1[ri][0] = fmaf(xi, w1v[j].x, acc1[ri][0]);
                        acc1[ri][1] = fmaf(xi, w1v[j].y, acc1[ri][1]);
                        acc3[ri][0] = fmaf(xi, w3v[j].x, acc3[ri][0]);
                        acc3[ri][1] = fmaf(xi, w3v[j].y, acc3[ri][1]);
                    }
                }
            }
        }
    }

#pragma unroll
    for (int i = 0; i < 16; ++i) {
        int r = tq * 16 + i;
        if (r < rows && fvalid) {
            float a0 = acc1[i][0], a1 = acc1[i][1];
            float2 g;
            g.x = a0 * (1.f / (1.f + __expf(-a0))) * acc3[i][0];
            g.y = a1 * (1.f / (1.f + __expf(-a1))) * acc3[i][1];
            *(float2*)&G[(size_t)(off + m0 + r) * F + f] = g;
        }
    }
}

// ---------------- GEMM B: out += w * (G @ W2) ----------------
// block 256 thr; tile BM=64 rows x 128 d-cols. Thread: 16 rows x 2 cols.
template <int F, bool GATHER>
__global__ __launch_bounds__(256, 3) void gemmB(
    const float* __restrict__ G, const float* __restrict__ w2,
    const int* __restrict__ offsets, const int* __restrict__ counts,
    const int* __restrict__ slot_tok, const float* __restrict__ slot_w,
    float* __restrict__ out)
{
    int e = blockIdx.z;
    int off, n;
    if (GATHER) {
        off = offsets[e]; n = counts[e];
        if (n > BM * MTILES) n = BM * MTILES;
    } else { off = 0; n = NTOK; }
    int m0 = blockIdx.x * BM;
    if (m0 >= n) return;
    int rows = min(BM, n - m0);
    int d0 = blockIdx.y * 128;
    int tid = threadIdx.x;
    int dj = tid & 63, tq = tid >> 6;
    int d = d0 + dj * 2;

    __shared__ float gs[BM][64];          // 16 KB
    float acc[16][2];
#pragma unroll
    for (int i = 0; i < 16; ++i) { acc[i][0] = 0.f; acc[i][1] = 0.f; }

    const size_t wbase = GATHER ? ((size_t)e * F * D) : 0;

    for (int k0 = 0; k0 < F; k0 += 64) {
        __syncthreads();
        for (int i = tid; i < BM * 16; i += 256) {
            int r = i >> 4, c4 = (i & 15) * 4;
            int rc = min(r, rows - 1);
            *(float4*)&gs[r][c4] = *(const float4*)&G[(size_t)(off + m0 + rc) * F + k0 + c4];
        }
        __syncthreads();

        const float* w2p = w2 + wbase + (size_t)k0 * D + d;
#pragma unroll 2
        for (int kk = 0; kk < 64; kk += 4) {
            float2 wv[4];
#pragma unroll
            for (int j = 0; j < 4; ++j) wv[j] = *(const float2*)&w2p[(size_t)(kk + j) * D];
#pragma unroll
            for (int h = 0; h < 2; ++h) {
                float4 gv[8];
#pragma unroll
                for (int i = 0; i < 8; ++i) gv[i] = *(const float4*)&gs[tq * 16 + h * 8 + i][kk];
#pragma unroll
                for (int j = 0; j < 4; ++j) {
#pragma unroll
                    for (int i = 0; i < 8; ++i) {
                        float g = (j == 0) ? gv[i].x : (j == 1) ? gv[i].y : (j == 2) ? gv[i].z : gv[i].w;
                        int ri = h * 8 + i;
                        acc[ri][0] = fmaf(g, wv[j].x, acc[ri][0]);
                        acc[ri][1] = fmaf(g, wv[j].y, acc[ri][1]);
                    }
                }
            }
        }
    }

#pragma unroll
    for (int i = 0; i < 16; ++i) {
        int r = tq * 16 + i;
        if (r < rows) {
            if (GATHER) {
                int sl = off + m0 + r;
                int tok = slot_tok[sl];
                float tw = slot_w[sl];
                atomicAdd(&out[(size_t)tok * D + d], tw * acc[i][0]);
                atomicAdd(&out[(size_t)tok * D + d + 1], tw * acc[i][1]);
            } else {
                *(float2*)&out[(size_t)(m0 + r) * D + d] = make_float2(acc[i][0], acc[i][1]);
            }
        }
    }
}

// ---------------- Launch ----------------
extern "C" void kernel_launch(void* const* d_in, const int* in_sizes, int n_in,
                              void* d_out, int out_size, void* d_ws, size_t ws_size,
                              hipStream_t stream)
{
    const float* x   = (const float*)d_in[0];
    const float* wg  = (const float*)d_in[1];
    const float* gb  = (const float*)d_in[2];
    const float* w1s = (const float*)d_in[3];
    const float* w2s = (const float*)d_in[4];
    const float* w3s = (const float*)d_in[5];
    const float* w1r = (const float*)d_in[6];
    const float* w2r = (const float*)d_in[7];
    const float* w3r = (const float*)d_in[8];

    float* out = (float*)d_out;                 // [NTOK, D]
    float* scores = out + (size_t)NTOK * D;     // [NTOK, E]

    char* ws = (char*)d_ws;
    int*   sel_idx  = (int*)(ws + 0);           // 6144 ints
    float* sel_w    = (float*)(ws + 24576);     // 6144 floats
    int*   counts   = (int*)(ws + 49152);       // 64
    int*   cursor   = (int*)(ws + 49408);       // 64
    int*   offsets  = (int*)(ws + 49664);       // 64
    int*   slot_tok = (int*)(ws + 49920);       // 6144
    float* slot_w   = (float*)(ws + 74496);     // 6144
    float* G_r      = (float*)(ws + 131072);                                  // 6144*704 f32
    float* G_s      = (float*)(ws + 131072 + (size_t)NTOK * TOPK * F_R * 4);  // 1024*1408 f32

    hipMemsetAsync(counts, 0, 512, stream);     // counts + cursor

    gate_kernel<<<NTOK, 64, 0, stream>>>(x, wg, gb, scores, sel_idx, sel_w);
    count_kernel<<<24, 256, 0, stream>>>(sel_idx, counts);
    scan_kernel<<<1, 64, 0, stream>>>(counts, offsets);
    scatter_kernel<<<24, 256, 0, stream>>>(sel_idx, sel_w, offsets, cursor, slot_tok, slot_w);

    // routed experts: G = silu(X W1) * (X W3)
    gemmA<F_R, true><<<dim3(MTILES, 6, E), 256, 0, stream>>>(
        x, w1r, w3r, offsets, counts, slot_tok, G_r);
    // shared expert (F_S=1408 -> 11 f-tiles of 128)
    gemmA<F_S, false><<<dim3(NTOK / BM, 11, 1), 256, 0, stream>>>(
        x, w1s, w3s, offsets, counts, slot_tok, G_s);

    // shared expert writes out (plain store) first, routed atomic-adds after
    gemmB<F_S, false><<<dim3(NTOK / BM, 8, 1), 256, 0, stream>>>(
        G_s, w2s, offsets, counts, slot_tok, slot_w, out);
    gemmB<F_R, true><<<dim3(MTILES, 8, E), 256, 0, stream>>>(
        G_r, w2r, offsets, counts, slot_tok, slot_w, out);
}